// Round 15
// baseline (299.568 us; speedup 1.0000x reference)
//
#include <hip/hip_runtime.h>
#include <hip/hip_bf16.h>
#include <math.h>

#define NUM_CLUSTERS 16
#define HIDDEN 1024
#define BOT 128
#define NTOK 65536

typedef __attribute__((ext_vector_type(8))) short bf16x8;
typedef __attribute__((ext_vector_type(4))) float f32x4;

typedef __attribute__((address_space(3))) unsigned int lds_u32;
typedef const __attribute__((address_space(1))) unsigned int glb_u32;

__device__ __forceinline__ void gload16(const void* g, void* l) {
  __builtin_amdgcn_global_load_lds((glb_u32*)g, (lds_u32*)l, 16, 0, 0);
}

__device__ __forceinline__ unsigned short f2bf(float x) {
  union { float f; unsigned u; } v; v.f = x;
  unsigned r = v.u + 0x7fffu + ((v.u >> 16) & 1u);
  return (unsigned short)(r >> 16);
}

__device__ __forceinline__ bf16x8 pack8(float4 a, float4 b) {
  bf16x8 r;
  r[0] = (short)f2bf(a.x); r[1] = (short)f2bf(a.y);
  r[2] = (short)f2bf(a.z); r[3] = (short)f2bf(a.w);
  r[4] = (short)f2bf(b.x); r[5] = (short)f2bf(b.y);
  r[6] = (short)f2bf(b.z); r[7] = (short)f2bf(b.w);
  return r;
}

// short-index swizzle: XOR short-idx bits 3..5 with (row&7) -> 16B-chunk spread
#define SWZS(row, sidx) ((sidx) ^ (((row) & 7) << 3))

#define SCB() __builtin_amdgcn_sched_barrier(0)
#define VMW(n)                                          \
  do {                                                  \
    SCB();                                              \
    asm volatile("s_waitcnt vmcnt(" #n ")" ::: "memory"); \
    SCB();                                              \
  } while (0)
#define SBAR()                                  \
  do {                                          \
    SCB();                                      \
    __builtin_amdgcn_s_barrier();               \
    SCB();                                      \
  } while (0)
#define LGKM0() asm volatile("s_waitcnt lgkmcnt(0)" ::: "memory")

// bijective XCD-chunk swizzle (m204)
__device__ __forceinline__ int xcd_swz(int bid, int nwg) {
  const int nx = 8;
  int q = nwg / nx, r = nwg % nx;
  int xcd = bid % nx, idx = bid / nx;
  int b = (xcd < r) ? xcd * (q + 1) : r * (q + 1) + (xcd - r) * q;
  return b + idx;
}

// ---------------- prep kernels ----------------

__global__ void k_zero(int* p) {
  if (threadIdx.x < 64) p[threadIdx.x] = 0;
}

__global__ void k_hist(const int* __restrict__ ids, int* __restrict__ counts) {
  __shared__ int lh[NUM_CLUSTERS];
  if (threadIdx.x < NUM_CLUSTERS) lh[threadIdx.x] = 0;
  __syncthreads();
  int i = blockIdx.x * blockDim.x + threadIdx.x;
  int stride = gridDim.x * blockDim.x;
  for (; i < NTOK; i += stride) atomicAdd(&lh[ids[i]], 1);
  __syncthreads();
  if (threadIdx.x < NUM_CLUSTERS) atomicAdd(&counts[threadIdx.x], lh[threadIdx.x]);
}

__global__ void k_scan(const int* __restrict__ counts, int* __restrict__ offsets,
                       int* __restrict__ cursor) {
  if (threadIdx.x == 0 && blockIdx.x == 0) {
    int s = 0;
    for (int c = 0; c < NUM_CLUSTERS; ++c) {
      offsets[c] = s; cursor[c] = s; s += counts[c];
    }
    offsets[NUM_CLUSTERS] = s;
  }
}

__global__ void k_scatter(const int* __restrict__ ids, int* cursor,
                          int* __restrict__ perm) {
  __shared__ int lh[NUM_CLUSTERS], lbase[NUM_CLUSTERS];
  const int tid = threadIdx.x;
  if (tid < NUM_CLUSTERS) lh[tid] = 0;
  __syncthreads();
  const int i = blockIdx.x * 256 + tid;
  const int cc = ids[i];
  const int r = atomicAdd(&lh[cc], 1);
  __syncthreads();
  if (tid < NUM_CLUSTERS) lbase[tid] = atomicAdd(&cursor[tid], lh[tid]);
  __syncthreads();
  perm[lbase[cc] + r] = i;
}

// W1 [16][1024][128] -> per-(c,ks) 16KB swizzled images of W1^T [n=128][k=64]
__global__ void k_w1til(const float* __restrict__ W1, unsigned short* __restrict__ outw) {
  const int id = blockIdx.x * 256 + threadIdx.x;   // 262144 total
  const int c  = id >> 14;
  const int ks = (id >> 10) & 15;
  const int q  = id & 1023;
  const int o  = q << 4;                 // stored byte offset in image
  const int row = o >> 7;                // n
  const int lb  = (o & 127) ^ ((row & 7) << 4);
  const int k0  = ks * 64 + (lb >> 1);   // 8 consecutive k
  const float* src = W1 + ((size_t)c * HIDDEN + k0) * BOT + row;
  unsigned short v[8];
  #pragma unroll
  for (int j = 0; j < 8; ++j) v[j] = f2bf(src[(size_t)j * BOT]);
  *(uint4*)((char*)outw + ((size_t)(c * 16 + ks)) * 16384 + o) = *(const uint4*)v;
}

// W2 [16][128][1024] -> fragment-linear layout (64-col chunks):
// outw[((c*16 + nc)*16 + kk*4 + nf)*512 + l*8 + i] =
//   bf16(W2[c][kk*32 + (l>>4)*8 + i][nc*64 + nf*16 + (l&15)])
__global__ void k_w2lin(const float* __restrict__ W2, unsigned short* __restrict__ outw) {
  const int id = blockIdx.x * 256 + threadIdx.x;   // 262144 total
  const int c   = id >> 14;
  const int rem = id & 16383;
  const int fg  = rem >> 6;            // nc*16 + kk*4 + nf
  const int l   = rem & 63;
  const int nc  = fg >> 4, kk = (fg >> 2) & 3, nf = fg & 3;
  const int n   = nc * 64 + nf * 16 + (l & 15);
  const int k0  = kk * 32 + (l >> 4) * 8;
  const float* src = W2 + ((size_t)c * BOT + k0) * HIDDEN + n;
  unsigned short v[8];
  #pragma unroll
  for (int j = 0; j < 8; ++j) v[j] = f2bf(src[(size_t)j * HIDDEN]);
  *(uint4*)(outw + (size_t)id * 8) = *(const uint4*)v;
}

// W2 [16][128][1024] -> per-(c,nc) 16KB swizzled images (FALLBACK path only)
__global__ void k_w2til(const float* __restrict__ W2, unsigned short* __restrict__ outw) {
  const int id = blockIdx.x * 256 + threadIdx.x;
  const int c  = id >> 14;
  const int nc = (id >> 10) & 15;
  const int q  = id & 1023;
  const int o  = q << 4;
  const int row = o >> 8;
  const int lb  = (o & 255) ^ ((row & 7) << 4);
  const int b0  = lb >> 1;
  const int n   = nc * 64 + row;
  const float* src = W2 + ((size_t)c * BOT + b0) * HIDDEN + n;
  unsigned short v[8];
  #pragma unroll
  for (int j = 0; j < 8; ++j) v[j] = f2bf(src[(size_t)j * HIDDEN]);
  *(uint4*)((char*)outw + ((size_t)(c * 16 + nc)) * 16384 + o) = *(const uint4*)v;
}

// ---- common tile locator: TM tokens per tile ----
__device__ __forceinline__ bool locate(const int* offsets, int bid, int TMv,
                                       int& c, int& base, int& nvalid) {
  int t = bid;
  for (c = 0; c < NUM_CLUSTERS; ++c) {
    int cnt = offsets[c + 1] - offsets[c];
    int nt = (cnt + TMv - 1) / TMv;
    if (t < nt) {
      base = offsets[c] + t * TMv;
      nvalid = min(TMv, offsets[c + 1] - base);
      return true;
    }
    t -= nt;
  }
  return false;
}

// ---------------- FUSED: R12 structure + DRAM burst-batching ----------------
// Phase 1 = R12 (BK=64, 16 steps, 1 barrier/step) but A-loads batched 2 steps
// per visit (512B/row burst). Phase 2 = R12 chunks processed in PAIRS: hv/bv
// for 2 chunks loaded together, stores for 2 chunks issued together.

__global__ __launch_bounds__(512, 6) void k_fuse(
    const float* __restrict__ h, const float* __restrict__ b1g,
    const float* __restrict__ b2g, const unsigned short* __restrict__ W1til,
    const unsigned short* __restrict__ W2lin, const int* __restrict__ offsets,
    const int* __restrict__ perm, float* __restrict__ out) {

  __shared__ __align__(16) unsigned short sA[2][4096];   // ph1 A dbuf; ph2: sMid
  __shared__ __align__(16) unsigned short sB[2][8192];   // ph1 W1 dbuf; ph2 W2 dbuf
  __shared__ int sTok[64];

  const int tid = threadIdx.x;
  const int l = tid & 63, w = tid >> 6;
  const int lr = l & 15, lg = l >> 4;
  const int wr = w >> 2, wc = w & 3;        // phase-1 wave tiling
  const int row = tid >> 3, o8 = tid & 7;   // phase-1 A staging

  const int nwg = NTOK / 64 + NUM_CLUSTERS;
  int c, base, nvalid;
  if (!locate(offsets, xcd_swz(blockIdx.x, nwg), 64, c, base, nvalid)) return;

  if (tid < 64) sTok[tid] = perm[base + min(tid, nvalid - 1)];
  LGKM0();
  SBAR();

  const unsigned short* w1base = W1til + (size_t)c * 16 * 8192;
  const unsigned short* wlin   = W2lin + (size_t)c * 131072;
  const float* hrow = h + (long)sTok[row] * HIDDEN + o8 * 8;

  // ---------------- phase 1 prologue ----------------
  // batch regs: bA/bB each hold 2 K-steps (4 float4). bB prologue = steps {0,1}.
  float4 bA[4], bB[4];
  bB[0] = *(const float4*)(hrow);        bB[1] = *(const float4*)(hrow + 4);
  bB[2] = *(const float4*)(hrow + 64);   bB[3] = *(const float4*)(hrow + 68);
  SCB();
  gload16(w1base + tid * 8, &sB[0][tid * 8]);
  gload16(w1base + 4096 + tid * 8, &sB[0][4096 + tid * 8]);
  SCB();
  *(bf16x8*)&sA[0][SWZS(row, row * 64 + o8 * 8)] = pack8(bB[0], bB[1]);
  LGKM0();
  VMW(0);
  SBAR();

  f32x4 acc[2][2];
  #pragma unroll
  for (int i = 0; i < 2; ++i)
    #pragma unroll
    for (int j = 0; j < 2; ++j) { f32x4 z = {0.f, 0.f, 0.f, 0.f}; acc[i][j] = z; }

#define G1_MFMA(CUR)                                                          \
  do {                                                                        \
    _Pragma("unroll")                                                         \
    for (int kk = 0; kk < 2; ++kk) {                                          \
      bf16x8 af[2], bfr[2];                                                   \
      _Pragma("unroll")                                                       \
      for (int mf = 0; mf < 2; ++mf) {                                        \
        const int m = wr * 32 + mf * 16 + lr;                                 \
        af[mf] = *(const bf16x8*)&sA[CUR][SWZS(m, m * 64 + kk * 32 + lg * 8)];\
      }                                                                       \
      _Pragma("unroll")                                                       \
      for (int nf = 0; nf < 2; ++nf) {                                        \
        const int rn = wc * 32 + nf * 16 + lr;                                \
        bfr[nf] = *(const bf16x8*)&sB[CUR][SWZS(rn, rn * 64 + kk * 32 + lg * 8)]; \
      }                                                                       \
      _Pragma("unroll")                                                       \
      for (int mf = 0; mf < 2; ++mf)                                          \
        _Pragma("unroll")                                                     \
        for (int nf = 0; nf < 2; ++nf)                                        \
          acc[mf][nf] = __builtin_amdgcn_mfma_f32_16x16x32_bf16(              \
              af[mf], bfr[nf], acc[mf][nf], 0, 0, 0);                         \
    }                                                                         \
  } while (0)

  // ---------------- phase 1 main loop (16 K-steps, full unroll) ----------
  #pragma unroll
  for (int t = 0; t < 16; ++t) {
    const int cur = t & 1;
    if (t < 15) {
      const unsigned short* w1s = w1base + (t + 1) * 8192;
      gload16(w1s + tid * 8, &sB[cur ^ 1][tid * 8]);
      gload16(w1s + 4096 + tid * 8, &sB[cur ^ 1][4096 + tid * 8]);
      SCB();
    }
    // batched A loads: 2 steps per visit (512B/row DRAM burst)
    if ((t % 4) == 0 && t <= 12) {
      bA[0] = *(const float4*)(hrow + (t + 2) * 64);
      bA[1] = *(const float4*)(hrow + (t + 2) * 64 + 4);
      bA[2] = *(const float4*)(hrow + (t + 3) * 64);
      bA[3] = *(const float4*)(hrow + (t + 3) * 64 + 4);
      SCB();
    }
    if ((t % 4) == 2 && t <= 12) {
      bB[0] = *(const float4*)(hrow + (t + 2) * 64);
      bB[1] = *(const float4*)(hrow + (t + 2) * 64 + 4);
      bB[2] = *(const float4*)(hrow + (t + 3) * 64);
      bB[3] = *(const float4*)(hrow + (t + 3) * 64 + 4);
      SCB();
    }
    G1_MFMA(cur);
    if (t < 15) {
      // pack A(t+1); source batch is static per t%4
      const float4* ps = ((t % 4) == 0) ? (bB + 2)
                        : ((t % 4) == 1) ? (bA + 0)
                        : ((t % 4) == 2) ? (bA + 2)
                                         : (bB + 0);
      *(bf16x8*)&sA[cur ^ 1][SWZS(row, row * 64 + o8 * 8)] = pack8(ps[0], ps[1]);
      if ((t % 2) == 0 && t <= 12) { VMW(4); } else { VMW(0); }
      LGKM0();
      SBAR();
    }
  }
#undef G1_MFMA

  // ---------------- transition: issue ph2 B(0); gelu -> sMid ----------------
  unsigned short* sMid = &sA[0][0];   // 8192 shorts = 16KB, phase-1 sA is dead
  SBAR();   // all waves' phase-1 LDS reads complete
  gload16(wlin + tid * 8, &sB[0][tid * 8]);
  gload16(wlin + 4096 + tid * 8, &sB[0][4096 + tid * 8]);
  SCB();

  {
    float b1v[2];
    #pragma unroll
    for (int nf = 0; nf < 2; ++nf) b1v[nf] = b1g[c * BOT + wc * 32 + nf * 16 + lr];
    #pragma unroll
    for (int mf = 0; mf < 2; ++mf) {
      #pragma unroll
      for (int nf = 0; nf < 2; ++nf) {
        #pragma unroll
        for (int r = 0; r < 4; ++r) {
          float x = acc[mf][nf][r] + b1v[nf];
          float g = 0.5f * x * (1.0f + erff(x * 0.70710678118654752f));
          const int m = wr * 32 + mf * 16 + lg * 4 + r;
          const int n = wc * 32 + nf * 16 + lr;
          sMid[SWZS(m, m * 128 + n)] = f2bf(g);
        }
      }
    }
  }
  LGKM0();
  VMW(0);   // B(0) landed
  SBAR();   // sMid visible everywhere

  // ---------------- phase 2: 8 pairs of 64-col chunks ----------------
  const int wrow = (w & 3) * 16;   // wave's 16-token row block
  const int ch = w >> 2;           // col half of the 64-col chunk

  bf16x8 ma[4];
  {
    const int mrow = wrow + lr;
    #pragma unroll
    for (int kk = 0; kk < 4; ++kk)
      ma[kk] = *(const bf16x8*)&sMid[SWZS(mrow, mrow * 128 + kk * 32 + lg * 8)];
  }

  const float* hr[4];
  float* orp[4];
  #pragma unroll
  for (int r = 0; r < 4; ++r) {
    const long tk = (long)sTok[wrow + lg * 4 + r] * HIDDEN;
    hr[r] = h + tk;
    orp[r] = out + tk;
  }
  const float* b2c = b2g + c * HIDDEN;

  for (int p = 0; p < 8; ++p) {
    const int cbE = p * 128 + ch * 32;
    const int cbO = cbE + 64;
    // hv/bv for BOTH chunks of the pair (512B-window row visits)
    float hvE[2][4], hvO[2][4], bvE[2], bvO[2];
    #pragma unroll
    for (int r = 0; r < 4; ++r) {
      hvE[0][r] = hr[r][cbE + lr];
      hvE[1][r] = hr[r][cbE + 16 + lr];
      hvO[0][r] = hr[r][cbO + lr];
      hvO[1][r] = hr[r][cbO + 16 + lr];
    }
    bvE[0] = b2c[cbE + lr];      bvE[1] = b2c[cbE + 16 + lr];
    bvO[0] = b2c[cbO + lr];      bvO[1] = b2c[cbO + 16 + lr];
    SCB();
    // B(odd chunk) -> sB[1]
    {
      const unsigned short* ws2 = wlin + (2 * p + 1) * 8192;
      gload16(ws2 + tid * 8, &sB[1][tid * 8]);
      gload16(ws2 + 4096 + tid * 8, &sB[1][4096 + tid * 8]);
      SCB();
    }

    // MFMA even chunk from sB[0]
    f32x4 a2e[2];
    { f32x4 z = {0.f, 0.f, 0.f, 0.f}; a2e[0] = z; a2e[1] = z; }
    #pragma unroll
    for (int kk = 0; kk < 4; ++kk) {
      #pragma unroll
      for (int nf = 0; nf < 2; ++nf) {
        const bf16x8 bf =
            *(const bf16x8*)&sB[0][(kk * 4 + ch * 2 + nf) * 512 + l * 8];
        a2e[nf] = __builtin_amdgcn_mfma_f32_16x16x32_bf16(ma[kk], bf, a2e[nf], 0, 0, 0);
      }
    }
    VMW(0);   // B(odd) + hv complete (also drains prior pair's stores)
    SBAR();   // sB[0] reads done everywhere; sB[1] valid

    if (p < 7) {
      const unsigned short* ws2 = wlin + (2 * p + 2) * 8192;
      gload16(ws2 + tid * 8, &sB[0][tid * 8]);
      gload16(ws2 + 4096 + tid * 8, &sB[0][4096 + tid * 8]);
      SCB();
    }

    // MFMA odd chunk from sB[1]
    f32x4 a2o[2];
    { f32x4 z = {0.f, 0.f, 0.f, 0.f}; a2o[0] = z; a2o[1] = z; }
    #pragma unroll
    for (int kk = 0; kk < 4; ++kk) {
      #pragma unroll
      for (int nf = 0; nf < 2; ++nf) {
        const bf16x8 bf =
            *(const bf16x8*)&sB[1][(kk * 4 + ch * 2 + nf) * 512 + l * 8];
        a2o[nf] = __builtin_amdgcn_mfma_f32_16x16x32_bf16(ma[kk], bf, a2o[nf], 0, 0, 0);
      }
    }

    // stores for BOTH chunks (per row: 2x64B + 2x64B segments, back-to-back).
    // Unconditional clamped stores (rows >= nvalid duplicate row nvalid-1).
    #pragma unroll
    for (int r = 0; r < 4; ++r) {
      orp[r][cbE + lr]      = a2e[0][r] + hvE[0][r] + bvE[0];
      orp[r][cbE + 16 + lr] = a2e[1][r] + hvE[1][r] + bvE[1];
      orp[r][cbO + lr]      = a2o[0][r] + hvO[0][r] + bvO[0];
      orp[r][cbO + 16 + lr] = a2o[1][r] + hvO[1][r] + bvO[1];
    }
    if (p < 7) {
      VMW(16);  // drain B(next even); the 16 stores stay in flight
      SBAR();   // sB[1] reads done; next pair may overwrite it
    }
  }
}

// ---------------- fallback fused kernel (ws too small): TM=128 ----------------
#define FSWZ(row, sidx) ((sidx) ^ (((row) & 7) << 3))

__global__ __launch_bounds__(256, 2) void k_fused(
    const float* __restrict__ h, const float* __restrict__ b1g,
    const float* __restrict__ b2g, const unsigned short* __restrict__ W1til,
    const unsigned short* __restrict__ W2til, const int* __restrict__ offsets,
    const int* __restrict__ perm, float* __restrict__ out) {

  __shared__ __align__(16) unsigned short sAB[16384];
  __shared__ __align__(16) unsigned short sMid[16384];
  __shared__ int sTok[128];

  const int tid = threadIdx.x;
  const int l = tid & 63, w = tid >> 6;
  const int wr = w >> 1, wc = w & 1;
  const int lr = l & 15, lg = l >> 4;

  int c, base, nvalid;
  if (!locate(offsets, blockIdx.x, 128, c, base, nvalid)) return;

  if (tid < 128) sTok[tid] = perm[base + min(tid, nvalid - 1)];
  __syncthreads();

  const unsigned short* w1base = W1til + (size_t)c * 16 * 8192;
  const unsigned short* w2base = W2til + (size_t)c * 16 * 8192;

  const int arow = tid >> 1, ahalf = tid & 1;
  const long htok = (long)sTok[arow] * HIDDEN;

  f32x4 acc[4][4];
  #pragma unroll
  for (int i = 0; i < 4; ++i)
    #pragma unroll
    for (int j = 0; j < 4; ++j) { f32x4 z = {0.f, 0.f, 0.f, 0.f}; acc[i][j] = z; }

  for (int ks = 0; ks < 16; ++ks) {
    __syncthreads();
    const unsigned short* w1s = w1base + ks * 8192;
    #pragma unroll
    for (int j = 0; j < 4; ++j)
      gload16(w1s + j * 2048 + tid * 8, &sAB[8192 + j * 2048 + tid * 8]);
    {
      const float* hp = h + htok + ks * 64 + ahalf * 32;
      float4 v0 = *(const float4*)(hp + 0),  v1 = *(const float4*)(hp + 4);
      float4 v2 = *(const float4*)(hp + 8),  v3 = *(const float4*)(hp + 12);
      float4 v4 = *(const float4*)(hp + 16), v5 = *(const float4*)(hp + 20);
      float4 v6 = *(const float4*)(hp + 24), v7 = *(const float4*)(hp + 28);
      const int sb = arow * 64 + ahalf * 32;
      *(bf16x8*)&sAB[FSWZ(arow, sb + 0)]  = pack8(v0, v1);
      *(bf16x8*)&sAB[FSWZ(arow, sb + 8)]  = pack8(v2, v3);
      *(bf16x8*)&sAB[FSWZ(arow, sb + 16)] = pack8(v4, v5);
      *(bf16x8*)&sAB[FSWZ(arow, sb + 24)] = pack8(v6, v7);
    }
    __syncthreads();
    #pragma unroll
    for (int kk = 0; kk < 2; ++kk) {
      bf16x8 af[4], bfr[4];
      #pragma unroll
      for (int mf = 0; mf < 4; ++mf) {
        const int rw = wr * 64 + mf * 16 + lr;
        af[mf] = *(const bf16x8*)&sAB[FSWZ(rw, rw * 64 + kk * 32 + lg * 8)];
      }
      #pragma unroll
      for (int nf = 0; nf < 4; ++nf) {
        const int rn = wc * 64 + nf * 16 + lr;
        bfr[nf] = *(const bf16x8*)&sAB[8192 + FSWZ(rn, rn * 64 + kk * 32 + lg * 8)];
      }
      #pragma unroll
      for (int mf = 0; mf < 4; ++mf)
        #pragma unroll
        for (int nf = 0; nf < 4; ++nf)
          acc[mf][nf] = __builtin_amdgcn_mfma_f32_16x16x32_bf16(af[mf], bfr[nf], acc[mf][nf], 0, 0, 0);
    }
  }

  float b1v[4];
  #pragma unroll
  for (int nf = 0; nf < 4; ++nf) b1v[nf] = b1g[c * BOT + wc * 64 + nf * 16 + lr];
  #pragma unroll
  for (int mf = 0; mf < 4; ++mf)
    #pragma unroll
    for (int nf = 0; nf < 4; ++nf)
      #pragma unroll
      for (int r = 0; r < 4; ++r) {
        float x = acc[mf][nf][r] + b1v[nf];
        float g = 0.5f * x * (1.0f + erff(x * 0.70710678118654752f));
        const int m = wr * 64 + mf * 16 + lg * 4 + r;
        const int n = wc * 64 + nf * 16 + lr;
        sMid[FSWZ(m, m * 128 + n)] = f2bf(g);
      }

  for (int nc = 0; nc < 16; ++nc) {
    __syncthreads();
    #pragma unroll
    for (int j = 0; j < 4; ++j)
      gload16(w2base + nc * 8192 + j * 2048 + tid * 8, &sAB[j * 2048 + tid * 8]);
    __syncthreads();

    f32x4 a2[4][2];
    #pragma unroll
    for (int i = 0; i < 4; ++i)
      #pragma unroll
      for (int j = 0; j < 2; ++j) { f32x4 z = {0.f, 0.f, 0.f, 0.f}; a2[i][j] = z; }

    #pragma unroll
    for (int kk = 0; kk < 4; ++kk) {
      bf16x8 af[4], bfr[2];
      #pragma unroll
      for (int mf = 0; mf < 4; ++mf) {
        const int m = wr * 64 + mf * 16 + lr;
        af[mf] = *(const bf16x8*)&sMid[FSWZ(m, m * 128 + kk * 32 + lg * 8)];
      }
      #pragma unroll
      for (int nf = 0; nf < 2; ++nf) {
        const int rn = wc * 32 + nf * 16 + lr;
        bfr[nf] = *(const bf16x8*)&sAB[FSWZ(rn, rn * 128 + kk * 32 + lg * 8)];
      }
      #pragma unroll
      for (int mf = 0; mf < 4; ++mf)
        #pragma unroll
        for (int nf = 0; nf < 2; ++nf)
          a2[mf][nf] = __builtin_amdgcn_mfma_f32_16x16x32_bf16(af[mf], bfr[nf], a2[mf][nf], 0, 0, 0);
    }

    #pragma unroll
    for (int nf = 0; nf < 2; ++nf) {
      const int nn = nc * 64 + wc * 32 + nf * 16 + lr;
      const float b2v = b2g[c * HIDDEN + nn];
      #pragma unroll
      for (int mf = 0; mf < 4; ++mf)
        #pragma unroll
        for (int r = 0; r < 4; ++r) {
          const int m = wr * 64 + mf * 16 + lg * 4 + r;
          if (m < nvalid) {
            const long tk = (long)sTok[m] * HIDDEN;
            out[tk + nn] = h[tk + nn] + a2[mf][nf][r] + b2v;
          }
        }
    }
  }
}

// ---------------- launcher ----------------
extern "C" void kernel_launch(void* const* d_in, const int* in_sizes, int n_in,
                              void* d_out, int out_size, void* d_ws, size_t ws_size,
                              hipStream_t stream) {
  const float* h   = (const float*)d_in[0];
  const int*   ids = (const int*)d_in[1];
  const float* W1  = (const float*)d_in[2];
  const float* b1  = (const float*)d_in[3];
  const float* W2  = (const float*)d_in[4];
  const float* b2  = (const float*)d_in[5];
  float* out = (float*)d_out;

  char* ws = (char*)d_ws;
  int* counts  = (int*)ws;            // 16 ints
  int* cursor  = (int*)(ws + 64);     // 16 ints
  int* offsets = (int*)(ws + 128);    // 17 ints
  int* perm    = (int*)(ws + 256);    // 65536 ints, ends at 262400
  unsigned short* W1buf = (unsigned short*)(ws + 262400);             // 4 MB
  unsigned short* W2buf = W1buf + (size_t)16 * 16 * 8192;             // 4 MB
  const size_t need = 262400 + 2 * (size_t)16 * 16 * 8192 * 2;

  k_zero<<<1, 64, 0, stream>>>(counts);
  k_hist<<<256, 256, 0, stream>>>(ids, counts);
  k_scan<<<1, 64, 0, stream>>>(counts, offsets, cursor);
  k_scatter<<<NTOK / 256, 256, 0, stream>>>(ids, cursor, perm);
  k_w1til<<<1024, 256, 0, stream>>>(W1, W1buf);

  if (ws_size >= need) {
    k_w2lin<<<1024, 256, 0, stream>>>(W2, W2buf);
    const int nwg = NTOK / 64 + NUM_CLUSTERS;
    k_fuse<<<nwg, 512, 0, stream>>>(h, b1, b2, W1buf, W2buf, offsets, perm, out);
  } else {
    k_w2til<<<1024, 256, 0, stream>>>(W2, W2buf);
    k_fused<<<NTOK / 128 + NUM_CLUSTERS, 256, 0, stream>>>(
        h, b1, b2, W1buf, W2buf, offsets, perm, out);
  }
}

// Round 16
// 253.456 us; speedup vs baseline: 1.1819x; 1.1819x over previous
//
#include <hip/hip_runtime.h>
#include <hip/hip_bf16.h>
#include <math.h>

#define NUM_CLUSTERS 16
#define HIDDEN 1024
#define BOT 128
#define NTOK 65536

typedef __attribute__((ext_vector_type(8))) short bf16x8;
typedef __attribute__((ext_vector_type(4))) float f32x4;

typedef __attribute__((address_space(3))) unsigned int lds_u32;
typedef const __attribute__((address_space(1))) unsigned int glb_u32;

__device__ __forceinline__ void gload16(const void* g, void* l) {
  __builtin_amdgcn_global_load_lds((glb_u32*)g, (lds_u32*)l, 16, 0, 0);
}

__device__ __forceinline__ unsigned short f2bf(float x) {
  union { float f; unsigned u; } v; v.f = x;
  unsigned r = v.u + 0x7fffu + ((v.u >> 16) & 1u);
  return (unsigned short)(r >> 16);
}

__device__ __forceinline__ bf16x8 pack8(float4 a, float4 b) {
  bf16x8 r;
  r[0] = (short)f2bf(a.x); r[1] = (short)f2bf(a.y);
  r[2] = (short)f2bf(a.z); r[3] = (short)f2bf(a.w);
  r[4] = (short)f2bf(b.x); r[5] = (short)f2bf(b.y);
  r[6] = (short)f2bf(b.z); r[7] = (short)f2bf(b.w);
  return r;
}

// short-index swizzle: XOR short-idx bits 3..5 with (row&7) -> 16B-chunk spread
#define SWZS(row, sidx) ((sidx) ^ (((row) & 7) << 3))

#define SCB() __builtin_amdgcn_sched_barrier(0)
#define VMW(n)                                          \
  do {                                                  \
    SCB();                                              \
    asm volatile("s_waitcnt vmcnt(" #n ")" ::: "memory"); \
    SCB();                                              \
  } while (0)
#define SBAR()                                  \
  do {                                          \
    SCB();                                      \
    __builtin_amdgcn_s_barrier();               \
    SCB();                                      \
  } while (0)
#define LGKM0() asm volatile("s_waitcnt lgkmcnt(0)" ::: "memory")

// bijective XCD-chunk swizzle (m204)
__device__ __forceinline__ int xcd_swz(int bid, int nwg) {
  const int nx = 8;
  int q = nwg / nx, r = nwg % nx;
  int xcd = bid % nx, idx = bid / nx;
  int b = (xcd < r) ? xcd * (q + 1) : r * (q + 1) + (xcd - r) * q;
  return b + idx;
}

// ---------------- prep kernels: STABLE cluster bucketing ----------------
// perm is sorted ascending (token id) within each cluster -> monotone DRAM
// sweeps in the fused kernel instead of random-page visits.

// 256 blocks x 256 threads: per-block cluster counts -> bcnt[c*256 + b]
__global__ void k_bcnt(const int* __restrict__ ids, int* __restrict__ bcnt) {
  __shared__ int lh[NUM_CLUSTERS];
  const int tid = threadIdx.x, b = blockIdx.x;
  if (tid < NUM_CLUSTERS) lh[tid] = 0;
  __syncthreads();
  atomicAdd(&lh[ids[b * 256 + tid]], 1);
  __syncthreads();
  if (tid < NUM_CLUSTERS) bcnt[tid * 256 + b] = lh[tid];
}

// 1 block: per-cluster exclusive scan over blocks + cluster bases
__global__ void k_bscan(const int* __restrict__ bcnt, int* __restrict__ bbase,
                        int* __restrict__ offsets) {
  __shared__ int tot[NUM_CLUSTERS];
  const int tid = threadIdx.x;
  if (tid < NUM_CLUSTERS) {
    int s = 0;
    for (int b = 0; b < 256; ++b) {
      bbase[tid * 256 + b] = s;
      s += bcnt[tid * 256 + b];
    }
    tot[tid] = s;
  }
  __syncthreads();
  if (tid == 0) {
    int s = 0;
    for (int c = 0; c < NUM_CLUSTERS; ++c) { offsets[c] = s; s += tot[c]; }
    offsets[NUM_CLUSTERS] = s;
  }
  __syncthreads();
  if (tid < NUM_CLUSTERS) {
    const int base = offsets[tid];
    for (int b = 0; b < 256; ++b) bbase[tid * 256 + b] += base;
  }
}

// 256 blocks x 256 threads: stable scatter (intra-block rank by thread id)
__global__ void k_sscat(const int* __restrict__ ids, const int* __restrict__ bbase,
                        int* __restrict__ perm) {
  __shared__ int sIds[256];
  const int tid = threadIdx.x, b = blockIdx.x;
  const int i = b * 256 + tid;
  const int c = ids[i];
  sIds[tid] = c;
  __syncthreads();
  int rank = 0;
  #pragma unroll 8
  for (int j = 0; j < 256; ++j) rank += (j < tid && sIds[j] == c) ? 1 : 0;
  perm[bbase[c * 256 + b] + rank] = i;
}

// W1 [16][1024][128] -> per-(c,ks) 16KB swizzled images of W1^T [n=128][k=64]
__global__ void k_w1til(const float* __restrict__ W1, unsigned short* __restrict__ outw) {
  const int id = blockIdx.x * 256 + threadIdx.x;   // 262144 total
  const int c  = id >> 14;
  const int ks = (id >> 10) & 15;
  const int q  = id & 1023;
  const int o  = q << 4;                 // stored byte offset in image
  const int row = o >> 7;                // n
  const int lb  = (o & 127) ^ ((row & 7) << 4);
  const int k0  = ks * 64 + (lb >> 1);   // 8 consecutive k
  const float* src = W1 + ((size_t)c * HIDDEN + k0) * BOT + row;
  unsigned short v[8];
  #pragma unroll
  for (int j = 0; j < 8; ++j) v[j] = f2bf(src[(size_t)j * BOT]);
  *(uint4*)((char*)outw + ((size_t)(c * 16 + ks)) * 16384 + o) = *(const uint4*)v;
}

// W2 [16][128][1024] -> fragment-linear layout (64-col chunks):
// outw[((c*16 + nc)*16 + kk*4 + nf)*512 + l*8 + i] =
//   bf16(W2[c][kk*32 + (l>>4)*8 + i][nc*64 + nf*16 + (l&15)])
__global__ void k_w2lin(const float* __restrict__ W2, unsigned short* __restrict__ outw) {
  const int id = blockIdx.x * 256 + threadIdx.x;   // 262144 total
  const int c   = id >> 14;
  const int rem = id & 16383;
  const int fg  = rem >> 6;            // nc*16 + kk*4 + nf
  const int l   = rem & 63;
  const int nc  = fg >> 4, kk = (fg >> 2) & 3, nf = fg & 3;
  const int n   = nc * 64 + nf * 16 + (l & 15);
  const int k0  = kk * 32 + (l >> 4) * 8;
  const float* src = W2 + ((size_t)c * BOT + k0) * HIDDEN + n;
  unsigned short v[8];
  #pragma unroll
  for (int j = 0; j < 8; ++j) v[j] = f2bf(src[(size_t)j * HIDDEN]);
  *(uint4*)(outw + (size_t)id * 8) = *(const uint4*)v;
}

// W2 -> per-(c,nc) 16KB swizzled images (FALLBACK path only)
__global__ void k_w2til(const float* __restrict__ W2, unsigned short* __restrict__ outw) {
  const int id = blockIdx.x * 256 + threadIdx.x;
  const int c  = id >> 14;
  const int nc = (id >> 10) & 15;
  const int q  = id & 1023;
  const int o  = q << 4;
  const int row = o >> 8;
  const int lb  = (o & 255) ^ ((row & 7) << 4);
  const int b0  = lb >> 1;
  const int n   = nc * 64 + row;
  const float* src = W2 + ((size_t)c * BOT + b0) * HIDDEN + n;
  unsigned short v[8];
  #pragma unroll
  for (int j = 0; j < 8; ++j) v[j] = f2bf(src[(size_t)j * HIDDEN]);
  *(uint4*)((char*)outw + ((size_t)(c * 16 + nc)) * 16384 + o) = *(const uint4*)v;
}

// ---- common tile locator: TM tokens per tile ----
__device__ __forceinline__ bool locate(const int* offsets, int bid, int TMv,
                                       int& c, int& base, int& nvalid) {
  int t = bid;
  for (c = 0; c < NUM_CLUSTERS; ++c) {
    int cnt = offsets[c + 1] - offsets[c];
    int nt = (cnt + TMv - 1) / TMv;
    if (t < nt) {
      base = offsets[c] + t * TMv;
      nvalid = min(TMv, offsets[c + 1] - base);
      return true;
    }
    t -= nt;
  }
  return false;
}

// ---------------- FUSED kernel: R12 structure, byte-for-byte ----------------
__global__ __launch_bounds__(512, 6) void k_fuse(
    const float* __restrict__ h, const float* __restrict__ b1g,
    const float* __restrict__ b2g, const unsigned short* __restrict__ W1til,
    const unsigned short* __restrict__ W2lin, const int* __restrict__ offsets,
    const int* __restrict__ perm, float* __restrict__ out) {

  __shared__ __align__(16) unsigned short sA[2][4096];   // ph1 A dbuf; ph2: sMid
  __shared__ __align__(16) unsigned short sB[2][8192];   // ph1 W1 dbuf; ph2 W2 dbuf
  __shared__ int sTok[64];

  const int tid = threadIdx.x;
  const int l = tid & 63, w = tid >> 6;
  const int lr = l & 15, lg = l >> 4;
  const int wr = w >> 2, wc = w & 3;        // phase-1 wave tiling
  const int row = tid >> 3, o8 = tid & 7;   // phase-1 A staging

  const int nwg = NTOK / 64 + NUM_CLUSTERS;
  int c, base, nvalid;
  if (!locate(offsets, xcd_swz(blockIdx.x, nwg), 64, c, base, nvalid)) return;

  if (tid < 64) sTok[tid] = perm[base + min(tid, nvalid - 1)];
  LGKM0();
  SBAR();

  const unsigned short* w1base = W1til + (size_t)c * 16 * 8192;
  const unsigned short* wlin   = W2lin + (size_t)c * 131072;
  const float* hrow = h + (long)sTok[row] * HIDDEN + o8 * 8;

  // ---------------- phase 1 ----------------
  float4 vaA[2], vaB[2];
  vaA[0] = *(const float4*)(hrow);       vaA[1] = *(const float4*)(hrow + 4);
  SCB();
  gload16(w1base + tid * 8, &sB[0][tid * 8]);
  gload16(w1base + 4096 + tid * 8, &sB[0][4096 + tid * 8]);
  SCB();
  vaB[0] = *(const float4*)(hrow + 64);  vaB[1] = *(const float4*)(hrow + 68);
  SCB();
  *(bf16x8*)&sA[0][SWZS(row, row * 64 + o8 * 8)] = pack8(vaA[0], vaA[1]);
  LGKM0();
  VMW(2);
  SBAR();

  f32x4 acc[2][2];
  #pragma unroll
  for (int i = 0; i < 2; ++i)
    #pragma unroll
    for (int j = 0; j < 2; ++j) { f32x4 z = {0.f, 0.f, 0.f, 0.f}; acc[i][j] = z; }

#define G1_MFMA(CUR)                                                          \
  do {                                                                        \
    _Pragma("unroll")                                                         \
    for (int kk = 0; kk < 2; ++kk) {                                          \
      bf16x8 af[2], bfr[2];                                                   \
      _Pragma("unroll")                                                       \
      for (int mf = 0; mf < 2; ++mf) {                                        \
        const int m = wr * 32 + mf * 16 + lr;                                 \
        af[mf] = *(const bf16x8*)&sA[CUR][SWZS(m, m * 64 + kk * 32 + lg * 8)];\
      }                                                                       \
      _Pragma("unroll")                                                       \
      for (int nf = 0; nf < 2; ++nf) {                                        \
        const int rn = wc * 32 + nf * 16 + lr;                                \
        bfr[nf] = *(const bf16x8*)&sB[CUR][SWZS(rn, rn * 64 + kk * 32 + lg * 8)]; \
      }                                                                       \
      _Pragma("unroll")                                                       \
      for (int mf = 0; mf < 2; ++mf)                                          \
        _Pragma("unroll")                                                     \
        for (int nf = 0; nf < 2; ++nf)                                        \
          acc[mf][nf] = __builtin_amdgcn_mfma_f32_16x16x32_bf16(              \
              af[mf], bfr[nf], acc[mf][nf], 0, 0, 0);                         \
    }                                                                         \
  } while (0)

  #pragma unroll
  for (int t = 0; t < 16; ++t) {
    const int cur = t & 1;
    if (t < 15) {
      const unsigned short* w1s = w1base + (t + 1) * 8192;
      gload16(w1s + tid * 8, &sB[cur ^ 1][tid * 8]);
      gload16(w1s + 4096 + tid * 8, &sB[cur ^ 1][4096 + tid * 8]);
      SCB();
    }
    if (t < 14) {
      if (t & 1) {
        vaB[0] = *(const float4*)(hrow + (t + 2) * 64);
        vaB[1] = *(const float4*)(hrow + (t + 2) * 64 + 4);
      } else {
        vaA[0] = *(const float4*)(hrow + (t + 2) * 64);
        vaA[1] = *(const float4*)(hrow + (t + 2) * 64 + 4);
      }
      SCB();
    }
    G1_MFMA(cur);
    if (t < 15) {
      const float4* src = ((t + 1) & 1) ? vaB : vaA;
      *(bf16x8*)&sA[cur ^ 1][SWZS(row, row * 64 + o8 * 8)] = pack8(src[0], src[1]);
      if (t < 14) { VMW(2); } else { VMW(0); }
      LGKM0();
      SBAR();
    }
  }
#undef G1_MFMA

  // ---------------- transition: issue ph2 B(0); gelu -> sMid ----------------
  unsigned short* sMid = &sA[0][0];   // 8192 shorts = 16KB, phase-1 sA is dead
  gload16(wlin + tid * 8, &sB[0][tid * 8]);
  gload16(wlin + 4096 + tid * 8, &sB[0][4096 + tid * 8]);
  SCB();
  SBAR();   // all waves' phase-1 LDS reads complete

  {
    float b1v[2];
    #pragma unroll
    for (int nf = 0; nf < 2; ++nf) b1v[nf] = b1g[c * BOT + wc * 32 + nf * 16 + lr];
    #pragma unroll
    for (int mf = 0; mf < 2; ++mf) {
      #pragma unroll
      for (int nf = 0; nf < 2; ++nf) {
        #pragma unroll
        for (int r = 0; r < 4; ++r) {
          float x = acc[mf][nf][r] + b1v[nf];
          float g = 0.5f * x * (1.0f + erff(x * 0.70710678118654752f));
          const int m = wr * 32 + mf * 16 + lg * 4 + r;
          const int n = wc * 32 + nf * 16 + lr;
          sMid[SWZS(m, m * 128 + n)] = f2bf(g);
        }
      }
    }
  }
  LGKM0();
  VMW(0);   // B(0) landed
  SBAR();   // sMid visible everywhere

  // ---------------- phase 2 ----------------
  const int wrow = (w & 3) * 16;   // wave's 16-token row block
  const int ch = w >> 2;           // col half of each 64-col chunk

  bf16x8 ma[4];
  {
    const int mrow = wrow + lr;
    #pragma unroll
    for (int kk = 0; kk < 4; ++kk)
      ma[kk] = *(const bf16x8*)&sMid[SWZS(mrow, mrow * 128 + kk * 32 + lg * 8)];
  }

  const float* hr[4];
  float* orp[4];
  #pragma unroll
  for (int r = 0; r < 4; ++r) {
    const long tk = (long)sTok[wrow + lg * 4 + r] * HIDDEN;
    hr[r] = h + tk;
    orp[r] = out + tk;
  }
  const float* b2c = b2g + c * HIDDEN;

  for (int nc = 0; nc < 16; ++nc) {
    const int cur = nc & 1;
    const int cb = nc * 64 + ch * 32;
    float hv[2][4], bv[2];
    #pragma unroll
    for (int nf = 0; nf < 2; ++nf)
      #pragma unroll
      for (int r = 0; r < 4; ++r)
        hv[nf][r] = hr[r][cb + nf * 16 + lr];
    #pragma unroll
    for (int nf = 0; nf < 2; ++nf) bv[nf] = b2c[cb + nf * 16 + lr];
    SCB();
    if (nc < 15) {
      const unsigned short* ws2 = wlin + (nc + 1) * 8192;
      gload16(ws2 + tid * 8, &sB[cur ^ 1][tid * 8]);
      gload16(ws2 + 4096 + tid * 8, &sB[cur ^ 1][4096 + tid * 8]);
      SCB();
    }

    f32x4 a2[2];
    { f32x4 z = {0.f, 0.f, 0.f, 0.f}; a2[0] = z; a2[1] = z; }
    #pragma unroll
    for (int kk = 0; kk < 4; ++kk) {
      #pragma unroll
      for (int nf = 0; nf < 2; ++nf) {
        const bf16x8 bf =
            *(const bf16x8*)&sB[cur][(kk * 4 + ch * 2 + nf) * 512 + l * 8];
        a2[nf] = __builtin_amdgcn_mfma_f32_16x16x32_bf16(ma[kk], bf, a2[nf], 0, 0, 0);
      }
    }

    #pragma unroll
    for (int nf = 0; nf < 2; ++nf) {
      #pragma unroll
      for (int r = 0; r < 4; ++r) {
        orp[r][cb + nf * 16 + lr] = a2[nf][r] + hv[nf][r] + bv[nf];
      }
    }
    if (nc < 15) {
      VMW(8);   // drain B(nc+1); the 8 stores stay in flight
      SBAR();   // everyone done with sB[cur]
    }
  }
}

// ---------------- fallback fused kernel (ws too small): TM=128 ----------------
#define FSWZ(row, sidx) ((sidx) ^ (((row) & 7) << 3))

__global__ __launch_bounds__(256, 2) void k_fused(
    const float* __restrict__ h, const float* __restrict__ b1g,
    const float* __restrict__ b2g, const unsigned short* __restrict__ W1til,
    const unsigned short* __restrict__ W2til, const int* __restrict__ offsets,
    const int* __restrict__ perm, float* __restrict__ out) {

  __shared__ __align__(16) unsigned short sAB[16384];
  __shared__ __align__(16) unsigned short sMid[16384];
  __shared__ int sTok[128];

  const int tid = threadIdx.x;
  const int l = tid & 63, w = tid >> 6;
  const int wr = w >> 1, wc = w & 1;
  const int lr = l & 15, lg = l >> 4;

  int c, base, nvalid;
  if (!locate(offsets, blockIdx.x, 128, c, base, nvalid)) return;

  if (tid < 128) sTok[tid] = perm[base + min(tid, nvalid - 1)];
  __syncthreads();

  const unsigned short* w1base = W1til + (size_t)c * 16 * 8192;
  const unsigned short* w2base = W2til + (size_t)c * 16 * 8192;

  const int arow = tid >> 1, ahalf = tid & 1;
  const long htok = (long)sTok[arow] * HIDDEN;

  f32x4 acc[4][4];
  #pragma unroll
  for (int i = 0; i < 4; ++i)
    #pragma unroll
    for (int j = 0; j < 4; ++j) { f32x4 z = {0.f, 0.f, 0.f, 0.f}; acc[i][j] = z; }

  for (int ks = 0; ks < 16; ++ks) {
    __syncthreads();
    const unsigned short* w1s = w1base + ks * 8192;
    #pragma unroll
    for (int j = 0; j < 4; ++j)
      gload16(w1s + j * 2048 + tid * 8, &sAB[8192 + j * 2048 + tid * 8]);
    {
      const float* hp = h + htok + ks * 64 + ahalf * 32;
      float4 v0 = *(const float4*)(hp + 0),  v1 = *(const float4*)(hp + 4);
      float4 v2 = *(const float4*)(hp + 8),  v3 = *(const float4*)(hp + 12);
      float4 v4 = *(const float4*)(hp + 16), v5 = *(const float4*)(hp + 20);
      float4 v6 = *(const float4*)(hp + 24), v7 = *(const float4*)(hp + 28);
      const int sb = arow * 64 + ahalf * 32;
      *(bf16x8*)&sAB[FSWZ(arow, sb + 0)]  = pack8(v0, v1);
      *(bf16x8*)&sAB[FSWZ(arow, sb + 8)]  = pack8(v2, v3);
      *(bf16x8*)&sAB[FSWZ(arow, sb + 16)] = pack8(v4, v5);
      *(bf16x8*)&sAB[FSWZ(arow, sb + 24)] = pack8(v6, v7);
    }
    __syncthreads();
    #pragma unroll
    for (int kk = 0; kk < 2; ++kk) {
      bf16x8 af[4], bfr[4];
      #pragma unroll
      for (int mf = 0; mf < 4; ++mf) {
        const int rw = wr * 64 + mf * 16 + lr;
        af[mf] = *(const bf16x8*)&sAB[FSWZ(rw, rw * 64 + kk * 32 + lg * 8)];
      }
      #pragma unroll
      for (int nf = 0; nf < 4; ++nf) {
        const int rn = wc * 64 + nf * 16 + lr;
        bfr[nf] = *(const bf16x8*)&sAB[8192 + FSWZ(rn, rn * 64 + kk * 32 + lg * 8)];
      }
      #pragma unroll
      for (int mf = 0; mf < 4; ++mf)
        #pragma unroll
        for (int nf = 0; nf < 4; ++nf)
          acc[mf][nf] = __builtin_amdgcn_mfma_f32_16x16x32_bf16(af[mf], bfr[nf], acc[mf][nf], 0, 0, 0);
    }
  }

  float b1v[4];
  #pragma unroll
  for (int nf = 0; nf < 4; ++nf) b1v[nf] = b1g[c * BOT + wc * 64 + nf * 16 + lr];
  #pragma unroll
  for (int mf = 0; mf < 4; ++mf)
    #pragma unroll
    for (int nf = 0; nf < 4; ++nf)
      #pragma unroll
      for (int r = 0; r < 4; ++r) {
        float x = acc[mf][nf][r] + b1v[nf];
        float g = 0.5f * x * (1.0f + erff(x * 0.70710678118654752f));
        const int m = wr * 64 + mf * 16 + lg * 4 + r;
        const int n = wc * 64 + nf * 16 + lr;
        sMid[FSWZ(m, m * 128 + n)] = f2bf(g);
      }

  for (int nc = 0; nc < 16; ++nc) {
    __syncthreads();
    #pragma unroll
    for (int j = 0; j < 4; ++j)
      gload16(w2base + nc * 8192 + j * 2048 + tid * 8, &sAB[j * 2048 + tid * 8]);
    __syncthreads();

    f32x4 a2[4][2];
    #pragma unroll
    for (int i = 0; i < 4; ++i)
      #pragma unroll
      for (int j = 0; j < 2; ++j) { f32x4 z = {0.f, 0.f, 0.f, 0.f}; a2[i][j] = z; }

    #pragma unroll
    for (int kk = 0; kk < 4; ++kk) {
      bf16x8 af[4], bfr[2];
      #pragma unroll
      for (int mf = 0; mf < 4; ++mf) {
        const int m = wr * 64 + mf * 16 + lr;
        af[mf] = *(const bf16x8*)&sMid[FSWZ(m, m * 128 + kk * 32 + lg * 8)];
      }
      #pragma unroll
      for (int nf = 0; nf < 2; ++nf) {
        const int rn = wc * 32 + nf * 16 + lr;
        bfr[nf] = *(const bf16x8*)&sAB[FSWZ(rn, rn * 128 + kk * 32 + lg * 8)];
      }
      #pragma unroll
      for (int mf = 0; mf < 4; ++mf)
        #pragma unroll
        for (int nf = 0; nf < 2; ++nf)
          a2[mf][nf] = __builtin_amdgcn_mfma_f32_16x16x32_bf16(af[mf], bfr[nf], a2[mf][nf], 0, 0, 0);
    }

    #pragma unroll
    for (int nf = 0; nf < 2; ++nf) {
      const int nn = nc * 64 + wc * 32 + nf * 16 + lr;
      const float b2v = b2g[c * HIDDEN + nn];
      #pragma unroll
      for (int mf = 0; mf < 4; ++mf)
        #pragma unroll
        for (int r = 0; r < 4; ++r) {
          const int m = wr * 64 + mf * 16 + lg * 4 + r;
          if (m < nvalid) {
            const long tk = (long)sTok[m] * HIDDEN;
            out[tk + nn] = h[tk + nn] + a2[mf][nf][r] + b2v;
          }
        }
    }
  }
}

// ---------------- launcher ----------------
extern "C" void kernel_launch(void* const* d_in, const int* in_sizes, int n_in,
                              void* d_out, int out_size, void* d_ws, size_t ws_size,
                              hipStream_t stream) {
  const float* h   = (const float*)d_in[0];
  const int*   ids = (const int*)d_in[1];
  const float* W1  = (const float*)d_in[2];
  const float* b1  = (const float*)d_in[3];
  const float* W2  = (const float*)d_in[4];
  const float* b2  = (const float*)d_in[5];
  float* out = (float*)d_out;

  char* ws = (char*)d_ws;
  int* offsets = (int*)(ws + 128);    // 17 ints
  int* perm    = (int*)(ws + 256);    // 65536 ints, ends at 262400
  int* bcnt    = (int*)(ws + 262400);             // 16*256 ints = 16KB
  int* bbase   = (int*)(ws + 262400 + 16384);     // 16*256 ints = 16KB
  unsigned short* W1buf = (unsigned short*)(ws + 262400 + 32768);     // 4 MB
  unsigned short* W2buf = W1buf + (size_t)16 * 16 * 8192;             // 4 MB
  const size_t need = 262400 + 32768 + 2 * (size_t)16 * 16 * 8192 * 2;

  k_bcnt<<<256, 256, 0, stream>>>(ids, bcnt);
  k_bscan<<<1, 64, 0, stream>>>(bcnt, bbase, offsets);
  k_sscat<<<256, 256, 0, stream>>>(ids, bbase, perm);
  k_w1til<<<1024, 256, 0, stream>>>(W1, W1buf);

  if (ws_size >= need) {
    k_w2lin<<<1024, 256, 0, stream>>>(W2, W2buf);
    const int nwg = NTOK / 64 + NUM_CLUSTERS;
    k_fuse<<<nwg, 512, 0, stream>>>(h, b1, b2, W1buf, W2buf, offsets, perm, out);
  } else {
    k_w2til<<<1024, 256, 0, stream>>>(W2, W2buf);
    k_fused<<<NTOK / 128 + NUM_CLUSTERS, 256, 0, stream>>>(
        h, b1, b2, W1buf, W2buf, offsets, perm, out);
  }
}

// Round 17
// 249.752 us; speedup vs baseline: 1.1995x; 1.0148x over previous
//
#include <hip/hip_runtime.h>
#include <hip/hip_bf16.h>
#include <math.h>

#define NUM_CLUSTERS 16
#define HIDDEN 1024
#define BOT 128
#define NTOK 65536

typedef __attribute__((ext_vector_type(8))) short bf16x8;
typedef __attribute__((ext_vector_type(4))) float f32x4;

typedef __attribute__((address_space(3))) unsigned int lds_u32;
typedef const __attribute__((address_space(1))) unsigned int glb_u32;

__device__ __forceinline__ void gload16(const void* g, void* l) {
  __builtin_amdgcn_global_load_lds((glb_u32*)g, (lds_u32*)l, 16, 0, 0);
}

__device__ __forceinline__ unsigned short f2bf(float x) {
  union { float f; unsigned u; } v; v.f = x;
  unsigned r = v.u + 0x7fffu + ((v.u >> 16) & 1u);
  return (unsigned short)(r >> 16);
}

__device__ __forceinline__ bf16x8 pack8(float4 a, float4 b) {
  bf16x8 r;
  r[0] = (short)f2bf(a.x); r[1] = (short)f2bf(a.y);
  r[2] = (short)f2bf(a.z); r[3] = (short)f2bf(a.w);
  r[4] = (short)f2bf(b.x); r[5] = (short)f2bf(b.y);
  r[6] = (short)f2bf(b.z); r[7] = (short)f2bf(b.w);
  return r;
}

// short-index swizzle: XOR short-idx bits 3..5 with (row&7) -> 16B-chunk spread
#define SWZS(row, sidx) ((sidx) ^ (((row) & 7) << 3))

#define SCB() __builtin_amdgcn_sched_barrier(0)
#define VMW(n)                                          \
  do {                                                  \
    SCB();                                              \
    asm volatile("s_waitcnt vmcnt(" #n ")" ::: "memory"); \
    SCB();                                              \
  } while (0)
#define SBAR()                                  \
  do {                                          \
    SCB();                                      \
    __builtin_amdgcn_s_barrier();               \
    SCB();                                      \
  } while (0)
#define LGKM0() asm volatile("s_waitcnt lgkmcnt(0)" ::: "memory")

// bijective XCD-chunk swizzle (m204)
__device__ __forceinline__ int xcd_swz(int bid, int nwg) {
  const int nx = 8;
  int q = nwg / nx, r = nwg % nx;
  int xcd = bid % nx, idx = bid / nx;
  int b = (xcd < r) ? xcd * (q + 1) : r * (q + 1) + (xcd - r) * q;
  return b + idx;
}

// ---------------- prep kernels: STABLE cluster bucketing ----------------

__global__ void k_bcnt(const int* __restrict__ ids, int* __restrict__ bcnt) {
  __shared__ int lh[NUM_CLUSTERS];
  const int tid = threadIdx.x, b = blockIdx.x;
  if (tid < NUM_CLUSTERS) lh[tid] = 0;
  __syncthreads();
  atomicAdd(&lh[ids[b * 256 + tid]], 1);
  __syncthreads();
  if (tid < NUM_CLUSTERS) bcnt[tid * 256 + b] = lh[tid];
}

__global__ void k_bscan(const int* __restrict__ bcnt, int* __restrict__ bbase,
                        int* __restrict__ offsets) {
  __shared__ int tot[NUM_CLUSTERS];
  const int tid = threadIdx.x;
  if (tid < NUM_CLUSTERS) {
    int s = 0;
    for (int b = 0; b < 256; ++b) {
      bbase[tid * 256 + b] = s;
      s += bcnt[tid * 256 + b];
    }
    tot[tid] = s;
  }
  __syncthreads();
  if (tid == 0) {
    int s = 0;
    for (int c = 0; c < NUM_CLUSTERS; ++c) { offsets[c] = s; s += tot[c]; }
    offsets[NUM_CLUSTERS] = s;
  }
  __syncthreads();
  if (tid < NUM_CLUSTERS) {
    const int base = offsets[tid];
    for (int b = 0; b < 256; ++b) bbase[tid * 256 + b] += base;
  }
}

__global__ void k_sscat(const int* __restrict__ ids, const int* __restrict__ bbase,
                        int* __restrict__ perm) {
  __shared__ int sIds[256];
  const int tid = threadIdx.x, b = blockIdx.x;
  const int i = b * 256 + tid;
  const int c = ids[i];
  sIds[tid] = c;
  __syncthreads();
  int rank = 0;
  #pragma unroll 8
  for (int j = 0; j < 256; ++j) rank += (j < tid && sIds[j] == c) ? 1 : 0;
  perm[bbase[c * 256 + b] + rank] = i;
}

// MAIN path: W1 [16][1024][128] -> fragment-linear per-step layout.
// outw[id*8 .. id*8+7] for id = c*16384 + t*1024 + f*64 + l, f = wc*4+kk*2+nf:
//   = bf16(W1[c][t*64 + kk*32 + (l>>4)*8 + i][wc*32 + nf*16 + (l&15)])
__global__ void k_w1lin(const float* __restrict__ W1, unsigned short* __restrict__ outw) {
  const int id = blockIdx.x * 256 + threadIdx.x;   // 262144 total
  const int c   = id >> 14;
  const int rem = id & 16383;
  const int t   = rem >> 10;
  const int f   = (rem >> 6) & 15;
  const int l   = rem & 63;
  const int wc = f >> 2, kk = (f >> 1) & 1, nf = f & 1;
  const int rn = wc * 32 + nf * 16 + (l & 15);
  const int k0 = t * 64 + kk * 32 + (l >> 4) * 8;
  const float* src = W1 + ((size_t)c * HIDDEN + k0) * BOT + rn;
  unsigned short v[8];
  #pragma unroll
  for (int j = 0; j < 8; ++j) v[j] = f2bf(src[(size_t)j * BOT]);
  *(uint4*)(outw + (size_t)id * 8) = *(const uint4*)v;
}

// W2 [16][128][1024] -> fragment-linear layout (64-col chunks)
__global__ void k_w2lin(const float* __restrict__ W2, unsigned short* __restrict__ outw) {
  const int id = blockIdx.x * 256 + threadIdx.x;   // 262144 total
  const int c   = id >> 14;
  const int rem = id & 16383;
  const int fg  = rem >> 6;            // nc*16 + kk*4 + nf
  const int l   = rem & 63;
  const int nc  = fg >> 4, kk = (fg >> 2) & 3, nf = fg & 3;
  const int n   = nc * 64 + nf * 16 + (l & 15);
  const int k0  = kk * 32 + (l >> 4) * 8;
  const float* src = W2 + ((size_t)c * BOT + k0) * HIDDEN + n;
  unsigned short v[8];
  #pragma unroll
  for (int j = 0; j < 8; ++j) v[j] = f2bf(src[(size_t)j * HIDDEN]);
  *(uint4*)(outw + (size_t)id * 8) = *(const uint4*)v;
}

// FALLBACK path preps (old tiled layouts)
__global__ void k_w1til(const float* __restrict__ W1, unsigned short* __restrict__ outw) {
  const int id = blockIdx.x * 256 + threadIdx.x;
  const int c  = id >> 14;
  const int ks = (id >> 10) & 15;
  const int q  = id & 1023;
  const int o  = q << 4;
  const int row = o >> 7;
  const int lb  = (o & 127) ^ ((row & 7) << 4);
  const int k0  = ks * 64 + (lb >> 1);
  const float* src = W1 + ((size_t)c * HIDDEN + k0) * BOT + row;
  unsigned short v[8];
  #pragma unroll
  for (int j = 0; j < 8; ++j) v[j] = f2bf(src[(size_t)j * BOT]);
  *(uint4*)((char*)outw + ((size_t)(c * 16 + ks)) * 16384 + o) = *(const uint4*)v;
}

__global__ void k_w2til(const float* __restrict__ W2, unsigned short* __restrict__ outw) {
  const int id = blockIdx.x * 256 + threadIdx.x;
  const int c  = id >> 14;
  const int nc = (id >> 10) & 15;
  const int q  = id & 1023;
  const int o  = q << 4;
  const int row = o >> 8;
  const int lb  = (o & 255) ^ ((row & 7) << 4);
  const int b0  = lb >> 1;
  const int n   = nc * 64 + row;
  const float* src = W2 + ((size_t)c * BOT + b0) * HIDDEN + n;
  unsigned short v[8];
  #pragma unroll
  for (int j = 0; j < 8; ++j) v[j] = f2bf(src[(size_t)j * HIDDEN]);
  *(uint4*)((char*)outw + ((size_t)(c * 16 + nc)) * 16384 + o) = *(const uint4*)v;
}

// ---- common tile locator: TM tokens per tile ----
__device__ __forceinline__ bool locate(const int* offsets, int bid, int TMv,
                                       int& c, int& base, int& nvalid) {
  int t = bid;
  for (c = 0; c < NUM_CLUSTERS; ++c) {
    int cnt = offsets[c + 1] - offsets[c];
    int nt = (cnt + TMv - 1) / TMv;
    if (t < nt) {
      base = offsets[c] + t * TMv;
      nvalid = min(TMv, offsets[c + 1] - base);
      return true;
    }
    t -= nt;
  }
  return false;
}

// ---------------- FUSED kernel: R12 + reg-B phase 1 (distance-2 prefetch) ----
// Phase 1: B operand in REGISTERS from fragment-linear W1lin; F(t+2) issued
// after F(t) consumed -> ~2-step lookahead, no vmcnt waits in the loop.
// A staging via LDS dbuf unchanged. Phase 2 = R12 unchanged.

__global__ __launch_bounds__(512, 6) void k_fuse(
    const float* __restrict__ h, const float* __restrict__ b1g,
    const float* __restrict__ b2g, const unsigned short* __restrict__ W1lin,
    const unsigned short* __restrict__ W2lin, const int* __restrict__ offsets,
    const int* __restrict__ perm, float* __restrict__ out) {

  __shared__ __align__(16) unsigned short sA[2][4096];   // ph1 A dbuf; ph2: sMid
  __shared__ __align__(16) unsigned short sB[2][8192];   // ph2 W2 dbuf
  __shared__ int sTok[64];

  const int tid = threadIdx.x;
  const int l = tid & 63, w = tid >> 6;
  const int lr = l & 15, lg = l >> 4;
  const int wr = w >> 2, wc = w & 3;        // phase-1 wave tiling
  const int row = tid >> 3, o8 = tid & 7;   // phase-1 A staging

  const int nwg = NTOK / 64 + NUM_CLUSTERS;
  int c, base, nvalid;
  if (!locate(offsets, xcd_swz(blockIdx.x, nwg), 64, c, base, nvalid)) return;

  if (tid < 64) sTok[tid] = perm[base + min(tid, nvalid - 1)];
  LGKM0();
  SBAR();

  const unsigned short* wfrag = W1lin + (size_t)c * 131072 + (wc * 4) * 512 + l * 8;
  const unsigned short* wlin  = W2lin + (size_t)c * 131072;
  const float* hrow = h + (long)sTok[row] * HIDDEN + o8 * 8;

  // ---------------- phase 1 prologue ----------------
  bf16x8 rBA[4], rBB[4];
#define LOADF(DST, T)                                                  \
  do {                                                                 \
    _Pragma("unroll")                                                  \
    for (int j = 0; j < 4; ++j)                                        \
      DST[j] = *(const bf16x8*)(wfrag + (T) * 8192 + j * 512);         \
    SCB();                                                             \
  } while (0)

  float4 vaA[2], vaB[2];
  vaA[0] = *(const float4*)(hrow);       vaA[1] = *(const float4*)(hrow + 4);
  SCB();
  LOADF(rBA, 0);
  vaB[0] = *(const float4*)(hrow + 64);  vaB[1] = *(const float4*)(hrow + 68);
  SCB();
  LOADF(rBB, 1);
  *(bf16x8*)&sA[0][SWZS(row, row * 64 + o8 * 8)] = pack8(vaA[0], vaA[1]);
  LGKM0();
  SBAR();

  f32x4 acc[2][2];
  #pragma unroll
  for (int i = 0; i < 2; ++i)
    #pragma unroll
    for (int j = 0; j < 2; ++j) { f32x4 z = {0.f, 0.f, 0.f, 0.f}; acc[i][j] = z; }

#define G1_MFMA(CUR, RB)                                                      \
  do {                                                                        \
    _Pragma("unroll")                                                         \
    for (int kk = 0; kk < 2; ++kk) {                                          \
      bf16x8 af[2];                                                           \
      _Pragma("unroll")                                                       \
      for (int mf = 0; mf < 2; ++mf) {                                        \
        const int m = wr * 32 + mf * 16 + lr;                                 \
        af[mf] = *(const bf16x8*)&sA[CUR][SWZS(m, m * 64 + kk * 32 + lg * 8)];\
      }                                                                       \
      _Pragma("unroll")                                                       \
      for (int mf = 0; mf < 2; ++mf)                                          \
        _Pragma("unroll")                                                     \
        for (int nf = 0; nf < 2; ++nf)                                        \
          acc[mf][nf] = __builtin_amdgcn_mfma_f32_16x16x32_bf16(              \
              af[mf], RB[kk * 2 + nf], acc[mf][nf], 0, 0, 0);                 \
    }                                                                         \
  } while (0)

  // ---------------- phase 1 main loop (16 K-steps, full unroll) ----------
  #pragma unroll
  for (int t = 0; t < 16; ++t) {
    const int cur = t & 1;
    // h loads for step t+2 (distance-2)
    if (t < 14) {
      if (t & 1) {
        vaB[0] = *(const float4*)(hrow + (t + 2) * 64);
        vaB[1] = *(const float4*)(hrow + (t + 2) * 64 + 4);
      } else {
        vaA[0] = *(const float4*)(hrow + (t + 2) * 64);
        vaA[1] = *(const float4*)(hrow + (t + 2) * 64 + 4);
      }
      SCB();
    }
    // MFMA with current reg-B set
    if (cur == 0) { G1_MFMA(0, rBA); } else { G1_MFMA(1, rBB); }
    // refill the just-consumed set with F(t+2)
    if (t < 14) {
      if (cur == 0) { LOADF(rBA, t + 2); } else { LOADF(rBB, t + 2); }
    }
    // stage A(t+1) (compiler auto-waits its h loads), barrier
    if (t < 15) {
      const float4* src = ((t + 1) & 1) ? vaB : vaA;
      *(bf16x8*)&sA[cur ^ 1][SWZS(row, row * 64 + o8 * 8)] = pack8(src[0], src[1]);
      LGKM0();
      SBAR();
    }
  }
#undef G1_MFMA
#undef LOADF

  // ---------------- transition: issue ph2 B(0); gelu -> sMid ----------------
  unsigned short* sMid = &sA[0][0];   // 8192 shorts = 16KB, phase-1 sA is dead
  gload16(wlin + tid * 8, &sB[0][tid * 8]);
  gload16(wlin + 4096 + tid * 8, &sB[0][4096 + tid * 8]);
  SCB();
  SBAR();   // all waves' phase-1 LDS reads complete

  {
    float b1v[2];
    #pragma unroll
    for (int nf = 0; nf < 2; ++nf) b1v[nf] = b1g[c * BOT + wc * 32 + nf * 16 + lr];
    #pragma unroll
    for (int mf = 0; mf < 2; ++mf) {
      #pragma unroll
      for (int nf = 0; nf < 2; ++nf) {
        #pragma unroll
        for (int r = 0; r < 4; ++r) {
          float x = acc[mf][nf][r] + b1v[nf];
          float g = 0.5f * x * (1.0f + erff(x * 0.70710678118654752f));
          const int m = wr * 32 + mf * 16 + lg * 4 + r;
          const int n = wc * 32 + nf * 16 + lr;
          sMid[SWZS(m, m * 128 + n)] = f2bf(g);
        }
      }
    }
  }
  LGKM0();
  VMW(0);   // B(0) landed
  SBAR();   // sMid visible everywhere

  // ---------------- phase 2 (R12, unchanged) ----------------
  const int wrow = (w & 3) * 16;   // wave's 16-token row block
  const int ch = w >> 2;           // col half of each 64-col chunk

  bf16x8 ma[4];
  {
    const int mrow = wrow + lr;
    #pragma unroll
    for (int kk = 0; kk < 4; ++kk)
      ma[kk] = *(const bf16x8*)&sMid[SWZS(mrow, mrow * 128 + kk * 32 + lg * 8)];
  }

  const float* hr[4];
  float* orp[4];
  #pragma unroll
  for (int r = 0; r < 4; ++r) {
    const long tk = (long)sTok[wrow + lg * 4 + r] * HIDDEN;
    hr[r] = h + tk;
    orp[r] = out + tk;
  }
  const float* b2c = b2g + c * HIDDEN;

  for (int nc = 0; nc < 16; ++nc) {
    const int cur = nc & 1;
    const int cb = nc * 64 + ch * 32;
    float hv[2][4], bv[2];
    #pragma unroll
    for (int nf = 0; nf < 2; ++nf)
      #pragma unroll
      for (int r = 0; r < 4; ++r)
        hv[nf][r] = hr[r][cb + nf * 16 + lr];
    #pragma unroll
    for (int nf = 0; nf < 2; ++nf) bv[nf] = b2c[cb + nf * 16 + lr];
    SCB();
    if (nc < 15) {
      const unsigned short* ws2 = wlin + (nc + 1) * 8192;
      gload16(ws2 + tid * 8, &sB[cur ^ 1][tid * 8]);
      gload16(ws2 + 4096 + tid * 8, &sB[cur ^ 1][4096 + tid * 8]);
      SCB();
    }

    f32x4 a2[2];
    { f32x4 z = {0.f, 0.f, 0.f, 0.f}; a2[0] = z; a2[1] = z; }
    #pragma unroll
    for (int kk = 0; kk < 4; ++kk) {
      #pragma unroll
      for (int nf = 0; nf < 2; ++nf) {
        const bf16x8 bf =
            *(const bf16x8*)&sB[cur][(kk * 4 + ch * 2 + nf) * 512 + l * 8];
        a2[nf] = __builtin_amdgcn_mfma_f32_16x16x32_bf16(ma[kk], bf, a2[nf], 0, 0, 0);
      }
    }

    #pragma unroll
    for (int nf = 0; nf < 2; ++nf) {
      #pragma unroll
      for (int r = 0; r < 4; ++r) {
        orp[r][cb + nf * 16 + lr] = a2[nf][r] + hv[nf][r] + bv[nf];
      }
    }
    if (nc < 15) {
      VMW(8);   // drain B(nc+1); the 8 stores stay in flight
      SBAR();   // everyone done with sB[cur]
    }
  }
}

// ---------------- fallback fused kernel (ws too small): TM=128 ----------------
#define FSWZ(row, sidx) ((sidx) ^ (((row) & 7) << 3))

__global__ __launch_bounds__(256, 2) void k_fused(
    const float* __restrict__ h, const float* __restrict__ b1g,
    const float* __restrict__ b2g, const unsigned short* __restrict__ W1til,
    const unsigned short* __restrict__ W2til, const int* __restrict__ offsets,
    const int* __restrict__ perm, float* __restrict__ out) {

  __shared__ __align__(16) unsigned short sAB[16384];
  __shared__ __align__(16) unsigned short sMid[16384];
  __shared__ int sTok[128];

  const int tid = threadIdx.x;
  const int l = tid & 63, w = tid >> 6;
  const int wr = w >> 1, wc = w & 1;
  const int lr = l & 15, lg = l >> 4;

  int c, base, nvalid;
  if (!locate(offsets, blockIdx.x, 128, c, base, nvalid)) return;

  if (tid < 128) sTok[tid] = perm[base + min(tid, nvalid - 1)];
  __syncthreads();

  const unsigned short* w1base = W1til + (size_t)c * 16 * 8192;
  const unsigned short* w2base = W2til + (size_t)c * 16 * 8192;

  const int arow = tid >> 1, ahalf = tid & 1;
  const long htok = (long)sTok[arow] * HIDDEN;

  f32x4 acc[4][4];
  #pragma unroll
  for (int i = 0; i < 4; ++i)
    #pragma unroll
    for (int j = 0; j < 4; ++j) { f32x4 z = {0.f, 0.f, 0.f, 0.f}; acc[i][j] = z; }

  for (int ks = 0; ks < 16; ++ks) {
    __syncthreads();
    const unsigned short* w1s = w1base + ks * 8192;
    #pragma unroll
    for (int j = 0; j < 4; ++j)
      gload16(w1s + j * 2048 + tid * 8, &sAB[8192 + j * 2048 + tid * 8]);
    {
      const float* hp = h + htok + ks * 64 + ahalf * 32;
      float4 v0 = *(const float4*)(hp + 0),  v1 = *(const float4*)(hp + 4);
      float4 v2 = *(const float4*)(hp + 8),  v3 = *(const float4*)(hp + 12);
      float4 v4 = *(const float4*)(hp + 16), v5 = *(const float4*)(hp + 20);
      float4 v6 = *(const float4*)(hp + 24), v7 = *(const float4*)(hp + 28);
      const int sb = arow * 64 + ahalf * 32;
      *(bf16x8*)&sAB[FSWZ(arow, sb + 0)]  = pack8(v0, v1);
      *(bf16x8*)&sAB[FSWZ(arow, sb + 8)]  = pack8(v2, v3);
      *(bf16x8*)&sAB[FSWZ(arow, sb + 16)] = pack8(v4, v5);
      *(bf16x8*)&sAB[FSWZ(arow, sb + 24)] = pack8(v6, v7);
    }
    __syncthreads();
    #pragma unroll
    for (int kk = 0; kk < 2; ++kk) {
      bf16x8 af[4], bfr[4];
      #pragma unroll
      for (int mf = 0; mf < 4; ++mf) {
        const int rw = wr * 64 + mf * 16 + lr;
        af[mf] = *(const bf16x8*)&sAB[FSWZ(rw, rw * 64 + kk * 32 + lg * 8)];
      }
      #pragma unroll
      for (int nf = 0; nf < 4; ++nf) {
        const int rn = wc * 64 + nf * 16 + lr;
        bfr[nf] = *(const bf16x8*)&sAB[8192 + FSWZ(rn, rn * 64 + kk * 32 + lg * 8)];
      }
      #pragma unroll
      for (int mf = 0; mf < 4; ++mf)
        #pragma unroll
        for (int nf = 0; nf < 4; ++nf)
          acc[mf][nf] = __builtin_amdgcn_mfma_f32_16x16x32_bf16(af[mf], bfr[nf], acc[mf][nf], 0, 0, 0);
    }
  }

  float b1v[4];
  #pragma unroll
  for (int nf = 0; nf < 4; ++nf) b1v[nf] = b1g[c * BOT + wc * 64 + nf * 16 + lr];
  #pragma unroll
  for (int mf = 0; mf < 4; ++mf)
    #pragma unroll
    for (int nf = 0; nf < 4; ++nf)
      #pragma unroll
      for (int r = 0; r < 4; ++r) {
        float x = acc[mf][nf][r] + b1v[nf];
        float g = 0.5f * x * (1.0f + erff(x * 0.70710678118654752f));
        const int m = wr * 64 + mf * 16 + lg * 4 + r;
        const int n = wc * 64 + nf * 16 + lr;
        sMid[FSWZ(m, m * 128 + n)] = f2bf(g);
      }

  for (int nc = 0; nc < 16; ++nc) {
    __syncthreads();
    #pragma unroll
    for (int j = 0; j < 4; ++j)
      gload16(w2base + nc * 8192 + j * 2048 + tid * 8, &sAB[j * 2048 + tid * 8]);
    __syncthreads();

    f32x4 a2[4][2];
    #pragma unroll
    for (int i = 0; i < 4; ++i)
      #pragma unroll
      for (int j = 0; j < 2; ++j) { f32x4 z = {0.f, 0.f, 0.f, 0.f}; a2[i][j] = z; }

    #pragma unroll
    for (int kk = 0; kk < 4; ++kk) {
      bf16x8 af[4], bfr[2];
      #pragma unroll
      for (int mf = 0; mf < 4; ++mf) {
        const int m = wr * 64 + mf * 16 + lr;
        af[mf] = *(const bf16x8*)&sMid[FSWZ(m, m * 128 + kk * 32 + lg * 8)];
      }
      #pragma unroll
      for (int nf = 0; nf < 2; ++nf) {
        const int rn = wc * 32 + nf * 16 + lr;
        bfr[nf] = *(const bf16x8*)&sAB[FSWZ(rn, rn * 128 + kk * 32 + lg * 8)];
      }
      #pragma unroll
      for (int mf = 0; mf < 4; ++mf)
        #pragma unroll
        for (int nf = 0; nf < 2; ++nf)
          a2[mf][nf] = __builtin_amdgcn_mfma_f32_16x16x32_bf16(af[mf], bfr[nf], a2[mf][nf], 0, 0, 0);
    }

    #pragma unroll
    for (int nf = 0; nf < 2; ++nf) {
      const int nn = nc * 64 + wc * 32 + nf * 16 + lr;
      const float b2v = b2g[c * HIDDEN + nn];
      #pragma unroll
      for (int mf = 0; mf < 4; ++mf)
        #pragma unroll
        for (int r = 0; r < 4; ++r) {
          const int m = wr * 64 + mf * 16 + lg * 4 + r;
          if (m < nvalid) {
            const long tk = (long)sTok[m] * HIDDEN;
            out[tk + nn] = h[tk + nn] + a2[mf][nf][r] + b2v;
          }
        }
    }
  }
}

// ---------------- launcher ----------------
extern "C" void kernel_launch(void* const* d_in, const int* in_sizes, int n_in,
                              void* d_out, int out_size, void* d_ws, size_t ws_size,
                              hipStream_t stream) {
  const float* h   = (const float*)d_in[0];
  const int*   ids = (const int*)d_in[1];
  const float* W1  = (const float*)d_in[2];
  const float* b1  = (const float*)d_in[3];
  const float* W2  = (const float*)d_in[4];
  const float* b2  = (const float*)d_in[5];
  float* out = (float*)d_out;

  char* ws = (char*)d_ws;
  int* offsets = (int*)(ws + 128);    // 17 ints
  int* perm    = (int*)(ws + 256);    // 65536 ints, ends at 262400
  int* bcnt    = (int*)(ws + 262400);             // 16*256 ints = 16KB
  int* bbase   = (int*)(ws + 262400 + 16384);     // 16*256 ints = 16KB
  unsigned short* W1buf = (unsigned short*)(ws + 262400 + 32768);     // 4 MB
  unsigned short* W2buf = W1buf + (size_t)16 * 16 * 8192;             // 4 MB
  const size_t need = 262400 + 32768 + 2 * (size_t)16 * 16 * 8192 * 2;

  k_bcnt<<<256, 256, 0, stream>>>(ids, bcnt);
  k_bscan<<<1, 64, 0, stream>>>(bcnt, bbase, offsets);
  k_sscat<<<256, 256, 0, stream>>>(ids, bbase, perm);

  if (ws_size >= need) {
    k_w1lin<<<1024, 256, 0, stream>>>(W1, W1buf);
    k_w2lin<<<1024, 256, 0, stream>>>(W2, W2buf);
    const int nwg = NTOK / 64 + NUM_CLUSTERS;
    k_fuse<<<nwg, 512, 0, stream>>>(h, b1, b2, W1buf, W2buf, offsets, perm, out);
  } else {
    k_w1til<<<1024, 256, 0, stream>>>(W1, W1buf);
    k_w2til<<<1024, 256, 0, stream>>>(W2, W2buf);
    k_fused<<<NTOK / 128 + NUM_CLUSTERS, 256, 0, stream>>>(
        h, b1, b2, W1buf, W2buf, offsets, perm, out);
  }
}